// Round 6
// baseline (892.557 us; speedup 1.0000x reference)
//
#include <hip/hip_runtime.h>
#include <hip/hip_bf16.h>
#include <math.h>

typedef __hip_bfloat16 bf16;

#define NBATCH 4
#define NPTS   8192
#define TOTPTS 32768
#define DIM    128
#define DOUT   256
#define KNN    16

__device__ __forceinline__ float b2f(bf16 x) { return __bfloat162float(x); }
__device__ __forceinline__ bf16 f2b(float x) { return __float2bfloat16(x); }

__device__ __forceinline__ float rsum32(float v) {
#pragma unroll
  for (int o = 16; o; o >>= 1) v += __shfl_down(v, o, 32);
  return v;
}

// ---------------------------------------------------------------------------
// Pack xyz -> (x, y, z, |p|^2) float4 (one coalesced 16B load per candidate).
// xyzw lives in the AOUT region of d_out (written only by attn, which runs
// after every xyzw reader has finished) so proj's Kf writes can proceed
// CONCURRENTLY with knn in the fused kernel below.
// ---------------------------------------------------------------------------
__global__ __launch_bounds__(256) void pack_kernel(const float* __restrict__ xyz,
                                                   float4* __restrict__ xyzw) {
  const int p = blockIdx.x * 256 + threadIdx.x;
  const float x = xyz[3 * p], y = xyz[3 * p + 1], z = xyz[3 * p + 2];
  xyzw[p] = make_float4(x, y, z, x * x + y * y + z * z);
}

// ---------------------------------------------------------------------------
// Segmented insert for KNN v4: the top-16 of query S lives in lanes
// [16S, 16S+15] (slot = lane&15, ascending). Serial over passing candidates;
// width-16 shfl_up keeps the shift inside the segment. Ascending index
// order + (bd <= dl) keep-condition == stable jax.lax.top_k tie semantics.
// ---------------------------------------------------------------------------
template <int S>
__device__ __forceinline__ void ins16(float d2, int g, int lane, int seg,
                                      float& bd, int& bi, float& tmax) {
  unsigned long long mask = __ballot(d2 < tmax);
  while (mask) {                          // wave-uniform loop
    const int l = __builtin_ctzll(mask);
    mask &= mask - 1;
    const float dl = __int_as_float(
        __builtin_amdgcn_readlane(__float_as_int(d2), l));
    if (dl < tmax) {                      // re-check vs tightened threshold
      const int il = g + l;
      const bool keep = bd <= dl;
      const float pd = __shfl_up(bd, 1, 16);    // segmented shift
      const int   pi = __shfl_up(bi, 1, 16);
      const bool fromPrev = ((lane & 15) > 0) && (pd > dl);
      const float nbd = keep ? bd : (fromPrev ? pd : dl);
      const int   nbi = keep ? bi : (fromPrev ? pi : il);
      bd = (seg == S) ? nbd : bd;         // only segment S updates
      bi = (seg == S) ? nbi : bi;
      tmax = __int_as_float(
          __builtin_amdgcn_readlane(__float_as_int(bd), S * 16 + 15));
    }
  }
}

// ---------------------------------------------------------------------------
// Fused KNN || Projections (round 6). proj depends only on feat+weights, not
// on knn -> run both in ONE launch so knn's latency-bound waves overlap
// proj's FMA-dense waves on the same CUs. Block mapping: bid % 3 == 0 -> knn
// (2048 blocks), else proj (4096 blocks), interleaved so both kinds
// co-reside from dispatch start. Bodies are unchanged from round 5.
// ---------------------------------------------------------------------------
__global__ __launch_bounds__(256) void knp_fused_kernel(
    const float4* __restrict__ xyzw, unsigned short* __restrict__ knn_out,
    const float* __restrict__ feat,
    const float* __restrict__ Wq, const float* __restrict__ bq,
    const float* __restrict__ Wk, const float* __restrict__ bk,
    const float* __restrict__ Wv, const float* __restrict__ bv,
    const float* __restrict__ g1, const float* __restrict__ b1,
    bf16* __restrict__ Q, bf16* __restrict__ Kf, bf16* __restrict__ Vf,
    float* __restrict__ skip) {
  __shared__ float f[8][DIM];             // proj branch only (~8.3 KB)
  __shared__ float ln[8][DIM];
  __shared__ float mu8[8], rs8[8];
  const int bid = blockIdx.x;
  const int tid = threadIdx.x;

  if (bid % 3 == 0) {
    // ------------------------- KNN body (v4) ------------------------------
    const int kid  = bid / 3;
    const int wid  = tid >> 6;
    const int lane = tid & 63;
    const int seg  = lane >> 4;
    const int q0 = (kid * 4 + wid) * 4;   // 4 consecutive queries
    const int b = q0 >> 13;
    const float4* cb = xyzw + (size_t)b * NPTS;

    const float4 mA = xyzw[q0 + 0];
    const float4 mB = xyzw[q0 + 1];
    const float4 mC = xyzw[q0 + 2];
    const float4 mD = xyzw[q0 + 3];

    float bd = INFINITY;
    int   bi = 0x7fff;
    float tA = INFINITY, tB = INFINITY, tC = INFINITY, tD = INFINITY;

    for (int g = 0; g < NPTS; g += 64) {
      const float4 t = cb[g + lane];
      const float dA = mA.w + t.w - 2.f * (mA.x * t.x + mA.y * t.y + mA.z * t.z);
      const float dB = mB.w + t.w - 2.f * (mB.x * t.x + mB.y * t.y + mB.z * t.z);
      const float dC = mC.w + t.w - 2.f * (mC.x * t.x + mC.y * t.y + mC.z * t.z);
      const float dD = mD.w + t.w - 2.f * (mD.x * t.x + mD.y * t.y + mD.z * t.z);
      ins16<0>(dA, g, lane, seg, bd, bi, tA);
      ins16<1>(dB, g, lane, seg, bd, bi, tB);
      ins16<2>(dC, g, lane, seg, bd, bi, tC);
      ins16<3>(dD, g, lane, seg, bd, bi, tD);
    }
    knn_out[(size_t)q0 * KNN + lane] = (unsigned short)bi;
    return;
  }

  // --------------------------- proj body ----------------------------------
  const int pid = bid - bid / 3 - 1;      // [0, 4096)
  const size_t r0 = (size_t)pid * 8;
  const float* src = feat + r0 * DIM;
#pragma unroll
  for (int i = 0; i < 4; i++) {
    const int idx = tid + i * 256;
    f[idx >> 7][idx & 127] = src[idx];
  }
  __syncthreads();
  const int r = tid >> 5, j = tid & 31;
  const float a0 = f[r][j], a1 = f[r][j + 32], a2 = f[r][j + 64], a3 = f[r][j + 96];
  float s = rsum32(a0 + a1 + a2 + a3);
  if (!j) mu8[r] = s * (1.f / 128.f);
  __syncthreads();
  const float mu = mu8[r];
  const float d0 = a0 - mu, d1 = a1 - mu, d2 = a2 - mu, d3 = a3 - mu;
  float ss = rsum32(d0 * d0 + d1 * d1 + d2 * d2 + d3 * d3);
  if (!j) rs8[r] = rsqrtf(ss * (1.f / 128.f) + 1e-5f);
  __syncthreads();
  const float rsd = rs8[r];
  ln[r][j]      = d0 * rsd * g1[j]      + b1[j];
  ln[r][j + 32] = d1 * rsd * g1[j + 32] + b1[j + 32];
  ln[r][j + 64] = d2 * rsd * g1[j + 64] + b1[j + 64];
  ln[r][j + 96] = d3 * rsd * g1[j + 96] + b1[j + 96];
  __syncthreads();
  float qa[8] = {}, ka[8] = {}, va[8] = {}, sa[8] = {};
  for (int d = 0; d < DIM; d += 4) {
    const float wq0 = Wq[(d + 0) * DOUT + tid], wq1 = Wq[(d + 1) * DOUT + tid];
    const float wq2 = Wq[(d + 2) * DOUT + tid], wq3 = Wq[(d + 3) * DOUT + tid];
    const float wk0 = Wk[(d + 0) * DOUT + tid], wk1 = Wk[(d + 1) * DOUT + tid];
    const float wk2 = Wk[(d + 2) * DOUT + tid], wk3 = Wk[(d + 3) * DOUT + tid];
    const float wv0 = Wv[(d + 0) * DOUT + tid], wv1 = Wv[(d + 1) * DOUT + tid];
    const float wv2 = Wv[(d + 2) * DOUT + tid], wv3 = Wv[(d + 3) * DOUT + tid];
#pragma unroll
    for (int rr = 0; rr < 8; rr++) {
      const float4 fv = *(const float4*)&f[rr][d];
      const float4 lv = *(const float4*)&ln[rr][d];
      qa[rr] += fv.x * wq0 + fv.y * wq1 + fv.z * wq2 + fv.w * wq3;
      ka[rr] += fv.x * wk0 + fv.y * wk1 + fv.z * wk2 + fv.w * wk3;
      va[rr] += fv.x * wv0 + fv.y * wv1 + fv.z * wv2 + fv.w * wv3;
      sa[rr] += lv.x * wq0 + lv.y * wq1 + lv.z * wq2 + lv.w * wq3;
    }
  }
  const float bqv = bq[tid], bkv = bk[tid], bvv = bv[tid];
#pragma unroll
  for (int rr = 0; rr < 8; rr++) {
    const size_t o = (r0 + rr) * DOUT + tid;
    Q[o]    = f2b(qa[rr] + bqv);
    Kf[o]   = f2b(ka[rr] + bkv);
    Vf[o]   = f2b(va[rr] + bvv);
    skip[o] = sa[rr] + bqv;
  }
}

// ---------------------------------------------------------------------------
// pos_kernel: the pos-MLP hoisted out of attn. Wave = point; lane = j/output
// dim. h1 (16 k-rows x 64) staged in LDS, pos phase reads h1 as wave-uniform
// broadcast ds_read_b128 (4 j's per op) so each Wp2 load is amortized over
// 16 rows. Output posG bf16[p][k][64].
// ---------------------------------------------------------------------------
__global__ __launch_bounds__(256) void pos_kernel(
    const float4* __restrict__ xyzw, const unsigned short* __restrict__ knn_in,
    const float* __restrict__ Wp1, const float* __restrict__ bp1,
    const float* __restrict__ Wp2, const float* __restrict__ bp2,
    bf16* __restrict__ posG) {
  __shared__ float h1S[4][16][64];        // 16 KB
  const int wid = threadIdx.x >> 6, lane = threadIdx.x & 63;
  const int p = blockIdx.x * 4 + wid;
  const int b = p >> 13, n = p & (NPTS - 1);
  const float4* cb = xyzw + (size_t)b * NPTS;
  const float4 me = cb[n];

  float rx = 0.f, ry = 0.f, rz = 0.f;
  if (lane < 16) {
    const int idx = knn_in[(size_t)p * KNN + lane];
    const float4 t = cb[idx];
    rx = t.x - me.x; ry = t.y - me.y; rz = t.z - me.z;
  }
  const float w0 = Wp1[lane], w1 = Wp1[64 + lane], w2 = Wp1[128 + lane];
  const float bb1 = bp1[lane], bb2 = bp2[lane];
#pragma unroll
  for (int k = 0; k < 16; k++) {
    const float r0 = __shfl(rx, k, 64);
    const float r1 = __shfl(ry, k, 64);
    const float r2 = __shfl(rz, k, 64);
    h1S[wid][k][lane] = fmaxf(bb1 + r0 * w0 + r1 * w1 + r2 * w2, 0.f);
  }
  __syncthreads();                        // cheap (4 waves); guards LDS RAW

  float acc[16];
#pragma unroll
  for (int k = 0; k < 16; k++) acc[k] = bb2;
  for (int jq = 0; jq < 16; jq++) {
    const float w2a = Wp2[(jq * 4 + 0) * 64 + lane];
    const float w2b = Wp2[(jq * 4 + 1) * 64 + lane];
    const float w2c = Wp2[(jq * 4 + 2) * 64 + lane];
    const float w2d = Wp2[(jq * 4 + 3) * 64 + lane];
#pragma unroll
    for (int k = 0; k < 16; k++) {
      const float4 h = *(const float4*)&h1S[wid][k][jq * 4];  // broadcast b128
      acc[k] += h.x * w2a + h.y * w2b + h.z * w2c + h.w * w2d;
    }
  }
#pragma unroll
  for (int k = 0; k < 16; k++)
    posG[((size_t)p * KNN + k) * 64 + lane] = f2b(acc[k]);
}

// ---------------------------------------------------------------------------
// Attention v3: pos-MLP removed (precomputed posG, bf16). One block per
// point, wave = head, lane = dim. K/V gathered into registers, posr streamed
// coalesced. Logits via 16-accumulator __shfl_xor butterfly (lane-redundant
// softmax, barrier-free). 1 barrier total. Also overwrites the xyzw overlay
// parked in AOUT (full overwrite of the region).
// ---------------------------------------------------------------------------
__global__ __launch_bounds__(256) void attn_kernel(
    const unsigned short* __restrict__ knn_in,
    bf16* __restrict__ QOA, const bf16* __restrict__ Kf, const bf16* __restrict__ Vf,
    const bf16* __restrict__ posG,
    float* __restrict__ AOUT) {
  __shared__ int nidxS[16];
  const int tid  = threadIdx.x;
  const int w    = tid >> 6;        // wave id = head
  const int lane = tid & 63;        // lane = dim within head
  const int p = blockIdx.x;
  const int b = p >> 13, n = p & (NPTS - 1);

  if (tid < 16) nidxS[tid] = knn_in[(size_t)p * KNN + tid];
  const float qreg = b2f(QOA[(size_t)p * DOUT + tid]);   // own row, pre-write
  __syncthreads();                  // nidxS ready

  // K/V gather + pos stream into registers
  float kreg[16], vreg[16], posr[16];
  const size_t rowbase = (size_t)b * NPTS;
  const bf16* pg = posG + (size_t)p * KNN * 64 + lane;
#pragma unroll
  for (int k = 0; k < 16; k++) {
    const size_t row = (rowbase + (size_t)nidxS[k]) * DOUT + tid;
    kreg[k] = b2f(Kf[row]);
    vreg[k] = b2f(Vf[row]);
    posr[k] = b2f(pg[k * 64]);
  }

  // logits: per-lane partials, butterfly reduce -> all lanes hold all 16
  float lg[16];
#pragma unroll
  for (int k = 0; k < 16; k++) lg[k] = qreg * (kreg[k] + posr[k]);
#pragma unroll
  for (int o = 32; o; o >>= 1) {
#pragma unroll
    for (int k = 0; k < 16; k++) lg[k] += __shfl_xor(lg[k], o, 64);
  }
  // softmax over k (lane-redundant, no sync)
  float m = -INFINITY;
#pragma unroll
  for (int k = 0; k < 16; k++) { lg[k] *= 0.125f; m = fmaxf(m, lg[k]); }
  float sum = 0.f;
#pragma unroll
  for (int k = 0; k < 16; k++) { lg[k] = expf(lg[k] - m); sum += lg[k]; }
  const float inv = 1.f / sum;
#pragma unroll
  for (int k = 0; k < 16; k++) lg[k] *= inv;
  // attn-weight store: lane l<16 writes a[l] (coalesced 64B per wave)
  float av = 0.f;
#pragma unroll
  for (int k = 0; k < 16; k++) if (lane == k) av = lg[k];
  if (lane < 16)
    AOUT[(((size_t)b * 4 + w) * NPTS + n) * KNN + lane] = av;
  // output: sum_k a[k] * (v[k] + pos[k][d]) -> overwrite own Q row
  float o = 0.f;
#pragma unroll
  for (int k = 0; k < 16; k++) o += lg[k] * (vreg[k] + posr[k]);
  QOA[(size_t)p * DOUT + tid] = f2b(o);
}

// ---------------------------------------------------------------------------
// FFN + LN2 + residual, v3: 32 rows/block, single aliased LDS buffer, 2
// output columns per thread (ds:FMA 1:8). Row pad +4 floats keeps b128
// alignment and staggers LN-phase banks. skip lives in d_out (f32; read
// then overwritten by the same thread/element).
// ---------------------------------------------------------------------------
#define FR2 32
#define DP  (DOUT + 4)
__global__ __launch_bounds__(256) void ffn_kernel(
    const bf16* __restrict__ OA,
    const float* __restrict__ Wf1, const float* __restrict__ bf1,
    const float* __restrict__ Wf2, const float* __restrict__ bf2,
    const float* __restrict__ g2, const float* __restrict__ b2p,
    float* __restrict__ out) {
  __shared__ float x[FR2][DP];            // 33.3 KB, triple-purposed
  __shared__ float mu32[FR2], rs32[FR2];
  const int tid = threadIdx.x;
  const int h = tid >> 7;                 // half: rows h*16 .. h*16+15
  const int t = tid & 127;
  const int c0 = t, c1 = t + 128;
  const int rbase = h * 16;
  const size_t r0 = (size_t)blockIdx.x * FR2;

  // stage: 32 rows x 256 cols bf16, vectorized ushort4 (8B/lane)
  const ushort4* s4 = (const ushort4*)(OA + r0 * DOUT);
#pragma unroll
  for (int i = 0; i < 8; i++) {
    const int c = tid + i * 256;          // 2048 ushort4 chunks
    const ushort4 u = s4[c];
    const int e = c * 4;
    const int row = e >> 8, col = e & 255;
    const bf16* pb = (const bf16*)&u;
    x[row][col + 0] = b2f(pb[0]);
    x[row][col + 1] = b2f(pb[1]);
    x[row][col + 2] = b2f(pb[2]);
    x[row][col + 3] = b2f(pb[3]);
  }
  __syncthreads();

  // fc1 = x @ Wf1 : 16 rows x 2 cols per thread
  float accA[16] = {}, accB[16] = {};
  for (int d = 0; d < DOUT; d += 4) {
    const float wa0 = Wf1[(d + 0) * DOUT + c0], wb0 = Wf1[(d + 0) * DOUT + c1];
    const float wa1 = Wf1[(d + 1) * DOUT + c0], wb1 = Wf1[(d + 1) * DOUT + c1];
    const float wa2 = Wf1[(d + 2) * DOUT + c0], wb2 = Wf1[(d + 2) * DOUT + c1];
    const float wa3 = Wf1[(d + 3) * DOUT + c0], wb3 = Wf1[(d + 3) * DOUT + c1];
#pragma unroll
    for (int rr = 0; rr < 16; rr++) {
      const float4 v = *(const float4*)&x[rbase + rr][d];   // broadcast b128
      accA[rr] += v.x * wa0 + v.y * wa1 + v.z * wa2 + v.w * wa3;
      accB[rr] += v.x * wb0 + v.y * wb1 + v.z * wb2 + v.w * wb3;
    }
  }
  __syncthreads();                        // all x reads done
  const float b1a = bf1[c0], b1b = bf1[c1];
#pragma unroll
  for (int rr = 0; rr < 16; rr++) {
    x[rbase + rr][c0] = fmaxf(accA[rr] + b1a, 0.f);   // y -> x
    x[rbase + rr][c1] = fmaxf(accB[rr] + b1b, 0.f);
  }
  __syncthreads();                        // y ready

  // fc2 = y @ Wf2
  float c2A[16] = {}, c2B[16] = {};
  for (int d = 0; d < DOUT; d += 4) {
    const float wa0 = Wf2[(d + 0) * DOUT + c0], wb0 = Wf2[(d + 0) * DOUT + c1];
    const float wa1 = Wf2[(d + 1) * DOUT + c0], wb1 = Wf2[(d + 1) * DOUT + c1];
    const float wa2 = Wf2[(d + 2) * DOUT + c0], wb2 = Wf2[(d + 2) * DOUT + c1];
    const float wa3 = Wf2[(d + 3) * DOUT + c0], wb3 = Wf2[(d + 3) * DOUT + c1];
#pragma unroll
    for (int rr = 0; rr < 16; rr++) {
      const float4 v = *(const float4*)&x[rbase + rr][d];
      c2A[rr] += v.x * wa0 + v.y * wa1 + v.z * wa2 + v.w * wa3;
      c2B[rr] += v.x * wb0 + v.y * wb1 + v.z * wb2 + v.w * wb3;
    }
  }
  __syncthreads();                        // all y reads done
  const float b2a = bf2[c0], b2b = bf2[c1];
#pragma unroll
  for (int rr = 0; rr < 16; rr++) {
    x[rbase + rr][c0] = c2A[rr] + b2a;    // fc2 -> x
    x[rbase + rr][c1] = c2B[rr] + b2b;
  }
  __syncthreads();                        // fc2 ready

  // LN2 stats: 8 threads per row, width-8 shfl reduce
  const int r = tid >> 3, j = tid & 7;
  float s = 0.f;
#pragma unroll
  for (int k2 = 0; k2 < 32; k2++) s += x[r][j + 8 * k2];
#pragma unroll
  for (int o = 4; o; o >>= 1) s += __shfl_down(s, o, 8);
  if (!j) mu32[r] = s * (1.f / 256.f);
  __syncthreads();
  const float mu = mu32[r];
  float ss = 0.f;
#pragma unroll
  for (int k2 = 0; k2 < 32; k2++) { const float dd = x[r][j + 8 * k2] - mu; ss += dd * dd; }
#pragma unroll
  for (int o = 4; o; o >>= 1) ss += __shfl_down(ss, o, 8);
  if (!j) rs32[r] = rsqrtf(ss * (1.f / 256.f) + 1e-5f);
  __syncthreads();

  const float gva = g2[c0], gvb = g2[c1], bba = b2p[c0], bbb = b2p[c1];
#pragma unroll
  for (int rr = 0; rr < 16; rr++) {
    const int row = rbase + rr;
    const float muv = mu32[row], rsv = rs32[row];
    const size_t o0 = (r0 + row) * DOUT + c0;
    const size_t o1 = (r0 + row) * DOUT + c1;
    const float sk0 = out[o0];            // skip stored here by proj
    const float sk1 = out[o1];
    out[o0] = (x[row][c0] - muv) * rsv * gva + bba + sk0;
    out[o1] = (x[row][c1] - muv) * rsv * gvb + bbb + sk1;
  }
}

extern "C" void kernel_launch(void* const* d_in, const int* in_sizes, int n_in,
                              void* d_out, int out_size, void* d_ws, size_t ws_size,
                              hipStream_t stream) {
  const float* xyz  = (const float*)d_in[0];
  const float* feat = (const float*)d_in[1];
  const float* Wq   = (const float*)d_in[2];
  const float* bq   = (const float*)d_in[3];
  const float* Wk   = (const float*)d_in[4];
  const float* bk   = (const float*)d_in[5];
  const float* Wv   = (const float*)d_in[6];
  const float* bv   = (const float*)d_in[7];
  const float* Wp1  = (const float*)d_in[8];
  const float* bp1  = (const float*)d_in[9];
  const float* Wp2  = (const float*)d_in[10];
  const float* bp2  = (const float*)d_in[11];
  const float* Wf1  = (const float*)d_in[12];
  const float* bf1  = (const float*)d_in[13];
  const float* Wf2  = (const float*)d_in[14];
  const float* bf2  = (const float*)d_in[15];
  const float* g1   = (const float*)d_in[16];
  const float* b1   = (const float*)d_in[17];
  const float* g2   = (const float*)d_in[18];
  const float* b2   = (const float*)d_in[19];

  float* out  = (float*)d_out;
  float* aout = out + (size_t)TOTPTS * DOUT;  // attn-weights output region (f32)

  // workspace layout (113 MB peak):
  //   [0, 1 MB)     final knn indices, uint16 (persists through attn)
  //   [1, 17 MB)    QOA bf16 (proj -> attn, aliased Q/out-rows)
  //   [17, 33 MB)   Kf bf16
  //   [33, 49 MB)   Vf bf16
  //   [49, 113 MB)  posG bf16 [TOTPTS][KNN][64] (pos -> attn)
  // xyzw (512 KB) is parked in the AOUT region of d_out: read by the fused
  // knn branch + pos, fully overwritten later by attn. This removes the old
  // Kf-region alias so proj can write Kf concurrently with knn.
  unsigned short* knn  = (unsigned short*)d_ws;
  float4*         xyzw = (float4*)aout;
  bf16* QOA  = (bf16*)((char*)d_ws + (size_t)(1 << 20));
  bf16* Kf   = QOA + (size_t)TOTPTS * DOUT;
  bf16* Vf   = Kf  + (size_t)TOTPTS * DOUT;
  bf16* posG = (bf16*)((char*)d_ws + (size_t)(49 << 20));

  pack_kernel<<<TOTPTS / 256, 256, 0, stream>>>(xyz, xyzw);
  knp_fused_kernel<<<TOTPTS / 16 + TOTPTS / 8, 256, 0, stream>>>(
      xyzw, knn, feat, Wq, bq, Wk, bk, Wv, bv, g1, b1, QOA, Kf, Vf, /*skip->*/out);
  pos_kernel<<<TOTPTS / 4, 256, 0, stream>>>(xyzw, knn, Wp1, bp1, Wp2, bp2, posG);
  attn_kernel<<<TOTPTS, 256, 0, stream>>>(knn, QOA, Kf, Vf, posG, aout);
  ffn_kernel<<<TOTPTS / FR2, 256, 0, stream>>>(QOA, Wf1, bf1, Wf2, bf2, g2, b2, out);
}

// Round 7
// 735.420 us; speedup vs baseline: 1.2137x; 1.2137x over previous
//
#include <hip/hip_runtime.h>
#include <hip/hip_bf16.h>
#include <math.h>

typedef __hip_bfloat16 bf16;
typedef __attribute__((ext_vector_type(8))) short short8v;   // 8 bf16 = 4 VGPR
typedef __attribute__((ext_vector_type(4))) float f32x4;

#define NBATCH 4
#define NPTS   8192
#define TOTPTS 32768
#define DIM    128
#define DOUT   256
#define KNN    16

__device__ __forceinline__ float b2f(bf16 x) { return __bfloat162float(x); }
__device__ __forceinline__ bf16 f2b(float x) { return __float2bfloat16(x); }

__device__ __forceinline__ float rsum32(float v) {
#pragma unroll
  for (int o = 16; o; o >>= 1) v += __shfl_down(v, o, 32);
  return v;
}

// ---------------------------------------------------------------------------
// Pack xyz -> (x, y, z, |p|^2) float4. xyzw parked in the AOUT region of
// d_out (read by knn/pos, fully overwritten later by attn).
// ---------------------------------------------------------------------------
__global__ __launch_bounds__(256) void pack_kernel(const float* __restrict__ xyz,
                                                   float4* __restrict__ xyzw) {
  const int p = blockIdx.x * 256 + threadIdx.x;
  const float x = xyz[3 * p], y = xyz[3 * p + 1], z = xyz[3 * p + 2];
  xyzw[p] = make_float4(x, y, z, x * x + y * y + z * z);
}

// ---------------------------------------------------------------------------
// Segmented insert for KNN v4 (round-5 proven): top-16 of query S in lanes
// [16S,16S+15], slot = lane&15 ascending. Stable jax.lax.top_k semantics.
// ---------------------------------------------------------------------------
template <int S>
__device__ __forceinline__ void ins16(float d2, int g, int lane, int seg,
                                      float& bd, int& bi, float& tmax) {
  unsigned long long mask = __ballot(d2 < tmax);
  while (mask) {                          // wave-uniform loop
    const int l = __builtin_ctzll(mask);
    mask &= mask - 1;
    const float dl = __int_as_float(
        __builtin_amdgcn_readlane(__float_as_int(d2), l));
    if (dl < tmax) {                      // re-check vs tightened threshold
      const int il = g + l;
      const bool keep = bd <= dl;
      const float pd = __shfl_up(bd, 1, 16);    // segmented shift
      const int   pi = __shfl_up(bi, 1, 16);
      const bool fromPrev = ((lane & 15) > 0) && (pd > dl);
      const float nbd = keep ? bd : (fromPrev ? pd : dl);
      const int   nbi = keep ? bi : (fromPrev ? pi : il);
      bd = (seg == S) ? nbd : bd;
      bi = (seg == S) ? nbi : bi;
      tmax = __int_as_float(
          __builtin_amdgcn_readlane(__float_as_int(bd), S * 16 + 15));
    }
  }
}

// ---------------------------------------------------------------------------
// KNN v4 (round-5 proven): 4 queries per wave, segmented top-16 lists.
// ---------------------------------------------------------------------------
__global__ __launch_bounds__(256) void knn_wave_kernel(
    const float4* __restrict__ xyzw, unsigned short* __restrict__ knn_out) {
  const int wid  = threadIdx.x >> 6;
  const int lane = threadIdx.x & 63;
  const int seg  = lane >> 4;
  const int q0 = (blockIdx.x * 4 + wid) * 4;
  const int b = q0 >> 13;
  const float4* cb = xyzw + (size_t)b * NPTS;

  const float4 mA = xyzw[q0 + 0];
  const float4 mB = xyzw[q0 + 1];
  const float4 mC = xyzw[q0 + 2];
  const float4 mD = xyzw[q0 + 3];

  float bd = INFINITY;
  int   bi = 0x7fff;
  float tA = INFINITY, tB = INFINITY, tC = INFINITY, tD = INFINITY;

  for (int g = 0; g < NPTS; g += 64) {
    const float4 t = cb[g + lane];
    const float dA = mA.w + t.w - 2.f * (mA.x * t.x + mA.y * t.y + mA.z * t.z);
    const float dB = mB.w + t.w - 2.f * (mB.x * t.x + mB.y * t.y + mB.z * t.z);
    const float dC = mC.w + t.w - 2.f * (mC.x * t.x + mC.y * t.y + mC.z * t.z);
    const float dD = mD.w + t.w - 2.f * (mD.x * t.x + mD.y * t.y + mD.z * t.z);
    ins16<0>(dA, g, lane, seg, bd, bi, tA);
    ins16<1>(dB, g, lane, seg, bd, bi, tB);
    ins16<2>(dC, g, lane, seg, bd, bi, tC);
    ins16<3>(dD, g, lane, seg, bd, bi, tD);
  }
  knn_out[(size_t)q0 * KNN + lane] = (unsigned short)bi;
}

// ---------------------------------------------------------------------------
// pos_kernel (round-2 proven): pos-MLP hoisted out of attn.
// ---------------------------------------------------------------------------
__global__ __launch_bounds__(256) void pos_kernel(
    const float4* __restrict__ xyzw, const unsigned short* __restrict__ knn_in,
    const float* __restrict__ Wp1, const float* __restrict__ bp1,
    const float* __restrict__ Wp2, const float* __restrict__ bp2,
    bf16* __restrict__ posG) {
  __shared__ float h1S[4][16][64];        // 16 KB
  const int wid = threadIdx.x >> 6, lane = threadIdx.x & 63;
  const int p = blockIdx.x * 4 + wid;
  const int b = p >> 13, n = p & (NPTS - 1);
  const float4* cb = xyzw + (size_t)b * NPTS;
  const float4 me = cb[n];

  float rx = 0.f, ry = 0.f, rz = 0.f;
  if (lane < 16) {
    const int idx = knn_in[(size_t)p * KNN + lane];
    const float4 t = cb[idx];
    rx = t.x - me.x; ry = t.y - me.y; rz = t.z - me.z;
  }
  const float w0 = Wp1[lane], w1 = Wp1[64 + lane], w2 = Wp1[128 + lane];
  const float bb1 = bp1[lane], bb2 = bp2[lane];
#pragma unroll
  for (int k = 0; k < 16; k++) {
    const float r0 = __shfl(rx, k, 64);
    const float r1 = __shfl(ry, k, 64);
    const float r2 = __shfl(rz, k, 64);
    h1S[wid][k][lane] = fmaxf(bb1 + r0 * w0 + r1 * w1 + r2 * w2, 0.f);
  }
  __syncthreads();

  float acc[16];
#pragma unroll
  for (int k = 0; k < 16; k++) acc[k] = bb2;
  for (int jq = 0; jq < 16; jq++) {
    const float w2a = Wp2[(jq * 4 + 0) * 64 + lane];
    const float w2b = Wp2[(jq * 4 + 1) * 64 + lane];
    const float w2c = Wp2[(jq * 4 + 2) * 64 + lane];
    const float w2d = Wp2[(jq * 4 + 3) * 64 + lane];
#pragma unroll
    for (int k = 0; k < 16; k++) {
      const float4 h = *(const float4*)&h1S[wid][k][jq * 4];  // broadcast b128
      acc[k] += h.x * w2a + h.y * w2b + h.z * w2c + h.w * w2d;
    }
  }
#pragma unroll
  for (int k = 0; k < 16; k++)
    posG[((size_t)p * KNN + k) * 64 + lane] = f2b(acc[k]);
}

// ---------------------------------------------------------------------------
// Projections (round-5 proven): per 8 rows LN1 + Q/K/V/skip.
// ---------------------------------------------------------------------------
__global__ __launch_bounds__(256) void proj_kernel(
    const float* __restrict__ feat,
    const float* __restrict__ Wq, const float* __restrict__ bq,
    const float* __restrict__ Wk, const float* __restrict__ bk,
    const float* __restrict__ Wv, const float* __restrict__ bv,
    const float* __restrict__ g1, const float* __restrict__ b1,
    bf16* __restrict__ Q, bf16* __restrict__ Kf, bf16* __restrict__ Vf,
    float* __restrict__ skip) {
  __shared__ float f[8][DIM];
  __shared__ float ln[8][DIM];
  __shared__ float mu8[8], rs8[8];
  const int tid = threadIdx.x;
  const size_t r0 = (size_t)blockIdx.x * 8;
  const float* src = feat + r0 * DIM;
#pragma unroll
  for (int i = 0; i < 4; i++) {
    const int idx = tid + i * 256;
    f[idx >> 7][idx & 127] = src[idx];
  }
  __syncthreads();
  const int r = tid >> 5, j = tid & 31;
  const float a0 = f[r][j], a1 = f[r][j + 32], a2 = f[r][j + 64], a3 = f[r][j + 96];
  float s = rsum32(a0 + a1 + a2 + a3);
  if (!j) mu8[r] = s * (1.f / 128.f);
  __syncthreads();
  const float mu = mu8[r];
  const float d0 = a0 - mu, d1 = a1 - mu, d2 = a2 - mu, d3 = a3 - mu;
  float ss = rsum32(d0 * d0 + d1 * d1 + d2 * d2 + d3 * d3);
  if (!j) rs8[r] = rsqrtf(ss * (1.f / 128.f) + 1e-5f);
  __syncthreads();
  const float rsd = rs8[r];
  ln[r][j]      = d0 * rsd * g1[j]      + b1[j];
  ln[r][j + 32] = d1 * rsd * g1[j + 32] + b1[j + 32];
  ln[r][j + 64] = d2 * rsd * g1[j + 64] + b1[j + 64];
  ln[r][j + 96] = d3 * rsd * g1[j + 96] + b1[j + 96];
  __syncthreads();
  float qa[8] = {}, ka[8] = {}, va[8] = {}, sa[8] = {};
  for (int d = 0; d < DIM; d += 4) {
    const float wq0 = Wq[(d + 0) * DOUT + tid], wq1 = Wq[(d + 1) * DOUT + tid];
    const float wq2 = Wq[(d + 2) * DOUT + tid], wq3 = Wq[(d + 3) * DOUT + tid];
    const float wk0 = Wk[(d + 0) * DOUT + tid], wk1 = Wk[(d + 1) * DOUT + tid];
    const float wk2 = Wk[(d + 2) * DOUT + tid], wk3 = Wk[(d + 3) * DOUT + tid];
    const float wv0 = Wv[(d + 0) * DOUT + tid], wv1 = Wv[(d + 1) * DOUT + tid];
    const float wv2 = Wv[(d + 2) * DOUT + tid], wv3 = Wv[(d + 3) * DOUT + tid];
#pragma unroll
    for (int rr = 0; rr < 8; rr++) {
      const float4 fv = *(const float4*)&f[rr][d];
      const float4 lv = *(const float4*)&ln[rr][d];
      qa[rr] += fv.x * wq0 + fv.y * wq1 + fv.z * wq2 + fv.w * wq3;
      ka[rr] += fv.x * wk0 + fv.y * wk1 + fv.z * wk2 + fv.w * wk3;
      va[rr] += fv.x * wv0 + fv.y * wv1 + fv.z * wv2 + fv.w * wv3;
      sa[rr] += lv.x * wq0 + lv.y * wq1 + lv.z * wq2 + lv.w * wq3;
    }
  }
  const float bqv = bq[tid], bkv = bk[tid], bvv = bv[tid];
#pragma unroll
  for (int rr = 0; rr < 8; rr++) {
    const size_t o = (r0 + rr) * DOUT + tid;
    Q[o]    = f2b(qa[rr] + bqv);
    Kf[o]   = f2b(ka[rr] + bkv);
    Vf[o]   = f2b(va[rr] + bvv);
    skip[o] = sa[rr] + bqv;
  }
}

// ---------------------------------------------------------------------------
// Attention v3 (round-2 proven).
// ---------------------------------------------------------------------------
__global__ __launch_bounds__(256) void attn_kernel(
    const unsigned short* __restrict__ knn_in,
    bf16* __restrict__ QOA, const bf16* __restrict__ Kf, const bf16* __restrict__ Vf,
    const bf16* __restrict__ posG,
    float* __restrict__ AOUT) {
  __shared__ int nidxS[16];
  const int tid  = threadIdx.x;
  const int w    = tid >> 6;
  const int lane = tid & 63;
  const int p = blockIdx.x;
  const int b = p >> 13, n = p & (NPTS - 1);

  if (tid < 16) nidxS[tid] = knn_in[(size_t)p * KNN + tid];
  const float qreg = b2f(QOA[(size_t)p * DOUT + tid]);
  __syncthreads();

  float kreg[16], vreg[16], posr[16];
  const size_t rowbase = (size_t)b * NPTS;
  const bf16* pg = posG + (size_t)p * KNN * 64 + lane;
#pragma unroll
  for (int k = 0; k < 16; k++) {
    const size_t row = (rowbase + (size_t)nidxS[k]) * DOUT + tid;
    kreg[k] = b2f(Kf[row]);
    vreg[k] = b2f(Vf[row]);
    posr[k] = b2f(pg[k * 64]);
  }

  float lg[16];
#pragma unroll
  for (int k = 0; k < 16; k++) lg[k] = qreg * (kreg[k] + posr[k]);
#pragma unroll
  for (int o = 32; o; o >>= 1) {
#pragma unroll
    for (int k = 0; k < 16; k++) lg[k] += __shfl_xor(lg[k], o, 64);
  }
  float m = -INFINITY;
#pragma unroll
  for (int k = 0; k < 16; k++) { lg[k] *= 0.125f; m = fmaxf(m, lg[k]); }
  float sum = 0.f;
#pragma unroll
  for (int k = 0; k < 16; k++) { lg[k] = expf(lg[k] - m); sum += lg[k]; }
  const float inv = 1.f / sum;
#pragma unroll
  for (int k = 0; k < 16; k++) lg[k] *= inv;
  float av = 0.f;
#pragma unroll
  for (int k = 0; k < 16; k++) if (lane == k) av = lg[k];
  if (lane < 16)
    AOUT[(((size_t)b * 4 + w) * NPTS + n) * KNN + lane] = av;
  float o = 0.f;
#pragma unroll
  for (int k = 0; k < 16; k++) o += lg[k] * (vreg[k] + posr[k]);
  QOA[(size_t)p * DOUT + tid] = f2b(o);
}

// ---------------------------------------------------------------------------
// wprep: one-time transpose+convert Wf1/Wf2 f32[k][c] -> bf16 Wt[c][k]
// (MFMA B-operand layout: lane reads 8 consecutive k at its column).
// Runs after attn; Wt lives in the dead Kf region. 16384 threads.
// ---------------------------------------------------------------------------
__global__ __launch_bounds__(256) void wprep_kernel(
    const float* __restrict__ Wf1, const float* __restrict__ Wf2,
    bf16* __restrict__ Wt1, bf16* __restrict__ Wt2) {
  const int t = blockIdx.x * 256 + threadIdx.x;          // [0, 16384)
  const float* src = (t & 8192) ? Wf2 : Wf1;
  bf16*        dst = (t & 8192) ? Wt2 : Wt1;
  const int rem = t & 8191;
  const int c = rem >> 5, k8 = (rem & 31) * 8;
#pragma unroll
  for (int j = 0; j < 8; j++)
    dst[c * 256 + k8 + j] = f2b(src[(k8 + j) * 256 + c]);
}

// ---------------------------------------------------------------------------
// FFN v4 (round 7): MFMA. 16 rows/block (2048 blocks), 4 waves; wave w owns
// cols [64w, 64w+64) as 4 16x16 tiles. mfma_f32_16x16x32_bf16 fragments
// (m92/m97-verified contiguous pattern): A: row=lane&15, k=8*(lane>>4)+i
// (one ds_read_b128); B: col=lane&15, same k (one global b128 from Wt[c][k]);
// C/D: col=lane&15, row=4*(lane>>4)+reg (m89-verified). LDS: bf16 x-tile |
// bf16 y-tile, aliased by f32 fc2 for the LN2 phase (barrier-separated).
// fc1/fc2 accumulate f32 in AGPR-backed frags; relu(fc1) stored bf16.
// skip lives in d_out (read then overwritten by the same thread/element).
// ---------------------------------------------------------------------------
#define FRB 16
#define FCP 264   // padded row stride (bf16 units); 528B = 132 dwords -> rows
                  // land on rotating banks (132 % 32 = 4), b128 16B-aligned
__global__ __launch_bounds__(256) void ffn_kernel(
    const bf16* __restrict__ OA,
    const bf16* __restrict__ Wt1, const float* __restrict__ bf1,
    const bf16* __restrict__ Wt2, const float* __restrict__ bf2,
    const float* __restrict__ g2, const float* __restrict__ b2p,
    float* __restrict__ out) {
  __shared__ float zs[FRB][FCP];          // 16896 B; aliased as xs|ys (bf16)
  __shared__ float mu16[FRB], rs16[FRB];
  bf16* base = (bf16*)&zs[0][0];          // xs: [0, FRB*FCP); ys: [FRB*FCP, 2*FRB*FCP)
  const int ysoff = FRB * FCP;
  const int tid  = threadIdx.x;
  const int w    = tid >> 6;
  const int lane = tid & 63;
  const int g    = lane >> 4, lr = lane & 15;
  const int cw   = w * 64;                // wave column base
  const size_t r0 = (size_t)blockIdx.x * FRB;

  // stage x: 16 rows x 256 bf16 (8 KB), 2 x 16B per thread, b128 LDS writes
  {
    const short8v* src = (const short8v*)(OA + r0 * DOUT);
#pragma unroll
    for (int i = 0; i < 2; i++) {
      const int ch = tid + i * 256;       // 512 chunks of 8 bf16
      const int row = ch >> 5, c8 = (ch & 31) * 8;
      *(short8v*)&base[row * FCP + c8] = src[ch];
    }
  }
  __syncthreads();

  f32x4 a0 = {0.f, 0.f, 0.f, 0.f}, a1 = a0, a2 = a0, a3 = a0;

#define GEMM8(OFF, WT)                                                         \
  _Pragma("unroll")                                                            \
  for (int s = 0; s < 8; s++) {                                                \
    const int k0 = s * 32 + g * 8;                                             \
    const short8v av = *(const short8v*)&base[(OFF) + lr * FCP + k0];          \
    a0 = __builtin_amdgcn_mfma_f32_16x16x32_bf16(                              \
        av, *(const short8v*)&(WT)[(cw +  0 + lr) * 256 + k0], a0, 0, 0, 0);   \
    a1 = __builtin_amdgcn_mfma_f32_16x16x32_bf16(                              \
        av, *(const short8v*)&(WT)[(cw + 16 + lr) * 256 + k0], a1, 0, 0, 0);   \
    a2 = __builtin_amdgcn_mfma_f32_16x16x32_bf16(                              \
        av, *(const short8v*)&(WT)[(cw + 32 + lr) * 256 + k0], a2, 0, 0, 0);   \
    a3 = __builtin_amdgcn_mfma_f32_16x16x32_bf16(                              \
        av, *(const short8v*)&(WT)[(cw + 48 + lr) * 256 + k0], a3, 0, 0, 0);   \
  }

  // fc1 = x @ Wf1
  GEMM8(0, Wt1)

  // relu(fc1 + bf1) -> ys (bf16); ys region disjoint from xs -> no pre-barrier
#define STORE_Y(ACC, T)                                                        \
  {                                                                            \
    const int c = cw + 16 * (T) + lr;                                          \
    const float bb = bf1[c];                                                   \
    _Pragma("unroll")                                                          \
    for (int e = 0; e < 4; e++)                                                \
      base[ysoff + (4 * g + e) * FCP + c] = f2b(fmaxf(ACC[e] + bb, 0.f));      \
  }
  STORE_Y(a0, 0) STORE_Y(a1, 1) STORE_Y(a2, 2) STORE_Y(a3, 3)
  __syncthreads();                        // ys ready

  // fc2 = y @ Wf2
  a0 = (f32x4){0.f, 0.f, 0.f, 0.f}; a1 = a0; a2 = a0; a3 = a0;
  GEMM8(ysoff, Wt2)
  __syncthreads();                        // all ys reads done (zs aliases it)

#define STORE_Z(ACC, T)                                                        \
  {                                                                            \
    const int c = cw + 16 * (T) + lr;                                          \
    const float bb = bf2[c];                                                   \
    _Pragma("unroll")                                                          \
    for (int e = 0; e < 4; e++) zs[4 * g + e][c] = ACC[e] + bb;                \
  }
  STORE_Z(a0, 0) STORE_Z(a1, 1) STORE_Z(a2, 2) STORE_Z(a3, 3)
  __syncthreads();                        // fc2 ready

  // LN2 stats: 16 threads per row, width-16 shfl reduce
  const int r = tid >> 4, j = tid & 15;
  float s = 0.f;
#pragma unroll
  for (int k2 = 0; k2 < 16; k2++) s += zs[r][j + 16 * k2];
#pragma unroll
  for (int o = 8; o; o >>= 1) s += __shfl_down(s, o, 16);
  if (!j) mu16[r] = s * (1.f / 256.f);
  __syncthreads();
  const float mu = mu16[r];
  float ss = 0.f;
#pragma unroll
  for (int k2 = 0; k2 < 16; k2++) { const float dd = zs[r][j + 16 * k2] - mu; ss += dd * dd; }
#pragma unroll
  for (int o = 8; o; o >>= 1) ss += __shfl_down(ss, o, 16);
  if (!j) rs16[r] = rsqrtf(ss * (1.f / 256.f) + 1e-5f);
  __syncthreads();

  const float gv = g2[tid], bbv = b2p[tid];
#pragma unroll
  for (int rr = 0; rr < FRB; rr++) {
    const size_t o = (r0 + rr) * DOUT + tid;
    const float sk = out[o];              // skip stored here by proj_kernel
    out[o] = (zs[rr][tid] - mu16[rr]) * rs16[rr] * gv + bbv + sk;
  }
}

extern "C" void kernel_launch(void* const* d_in, const int* in_sizes, int n_in,
                              void* d_out, int out_size, void* d_ws, size_t ws_size,
                              hipStream_t stream) {
  const float* xyz  = (const float*)d_in[0];
  const float* feat = (const float*)d_in[1];
  const float* Wq   = (const float*)d_in[2];
  const float* bq   = (const float*)d_in[3];
  const float* Wk   = (const float*)d_in[4];
  const float* bk   = (const float*)d_in[5];
  const float* Wv   = (const float*)d_in[6];
  const float* bv   = (const float*)d_in[7];
  const float* Wp1  = (const float*)d_in[8];
  const float* bp1  = (const float*)d_in[9];
  const float* Wp2  = (const float*)d_in[10];
  const float* bp2  = (const float*)d_in[11];
  const float* Wf1  = (const float*)d_in[12];
  const float* bf1  = (const float*)d_in[13];
  const float* Wf2  = (const float*)d_in[14];
  const float* bf2  = (const float*)d_in[15];
  const float* g1   = (const float*)d_in[16];
  const float* b1   = (const float*)d_in[17];
  const float* g2   = (const float*)d_in[18];
  const float* b2   = (const float*)d_in[19];

  float* out  = (float*)d_out;
  float* aout = out + (size_t)TOTPTS * DOUT;  // attn-weights output region

  // workspace layout (113 MB peak):
  //   [0, 1 MB)     knn indices u16
  //   [1, 17 MB)    QOA bf16 (proj -> attn-out, ffn input)
  //   [17, 33 MB)   Kf bf16; dead after attn -> reused for Wt1/Wt2 (wprep)
  //   [33, 49 MB)   Vf bf16
  //   [49, 113 MB)  posG bf16
  // xyzw (512 KB) parked in AOUT region of d_out (overwritten by attn).
  unsigned short* knn  = (unsigned short*)d_ws;
  float4*         xyzw = (float4*)aout;
  bf16* QOA  = (bf16*)((char*)d_ws + (size_t)(1 << 20));
  bf16* Kf   = QOA + (size_t)TOTPTS * DOUT;
  bf16* Vf   = Kf  + (size_t)TOTPTS * DOUT;
  bf16* posG = (bf16*)((char*)d_ws + (size_t)(49 << 20));
  bf16* Wt1  = Kf;                        // 128 KB, alive only after attn
  bf16* Wt2  = Kf + 65536;

  pack_kernel<<<TOTPTS / 256, 256, 0, stream>>>(xyz, xyzw);
  knn_wave_kernel<<<TOTPTS / 16, 256, 0, stream>>>(xyzw, knn);
  pos_kernel<<<TOTPTS / 4, 256, 0, stream>>>(xyzw, knn, Wp1, bp1, Wp2, bp2, posG);
  proj_kernel<<<TOTPTS / 8, 256, 0, stream>>>(feat, Wq, bq, Wk, bk, Wv, bv, g1, b1,
                                              QOA, Kf, Vf, /*skip->*/out);
  attn_kernel<<<TOTPTS, 256, 0, stream>>>(knn, QOA, Kf, Vf, posG, aout);
  wprep_kernel<<<64, 256, 0, stream>>>(Wf1, Wf2, Wt1, Wt2);
  ffn_kernel<<<TOTPTS / FRB, 256, 0, stream>>>(QOA, Wt1, bf1, Wt2, bf2, g2, b2, out);
}

// Round 8
// 684.294 us; speedup vs baseline: 1.3043x; 1.0747x over previous
//
#include <hip/hip_runtime.h>
#include <hip/hip_bf16.h>
#include <math.h>

typedef __hip_bfloat16 bf16;
typedef __attribute__((ext_vector_type(8))) short short8v;   // 8 bf16 = 4 VGPR
typedef __attribute__((ext_vector_type(4))) float f32x4;

#define NBATCH 4
#define NPTS   8192
#define TOTPTS 32768
#define DIM    128
#define DOUT   256
#define KNN    16

__device__ __forceinline__ float b2f(bf16 x) { return __bfloat162float(x); }
__device__ __forceinline__ bf16 f2b(float x) { return __float2bfloat16(x); }

__device__ __forceinline__ float rsum32(float v) {
#pragma unroll
  for (int o = 16; o; o >>= 1) v += __shfl_down(v, o, 32);
  return v;
}

// ---------------------------------------------------------------------------
// Pack xyz -> (x, y, z, |p|^2) float4. xyzw parked in the AOUT region of
// d_out (read by knn/pos, fully overwritten later by attn).
// ---------------------------------------------------------------------------
__global__ __launch_bounds__(256) void pack_kernel(const float* __restrict__ xyz,
                                                   float4* __restrict__ xyzw) {
  const int p = blockIdx.x * 256 + threadIdx.x;
  const float x = xyz[3 * p], y = xyz[3 * p + 1], z = xyz[3 * p + 2];
  xyzw[p] = make_float4(x, y, z, x * x + y * y + z * z);
}

// ---------------------------------------------------------------------------
// Segmented insert for KNN v4 (round-5 proven): top-16 of query S in lanes
// [16S,16S+15], slot = lane&15 ascending. Stable jax.lax.top_k semantics.
// ---------------------------------------------------------------------------
template <int S>
__device__ __forceinline__ void ins16(float d2, int g, int lane, int seg,
                                      float& bd, int& bi, float& tmax) {
  unsigned long long mask = __ballot(d2 < tmax);
  while (mask) {                          // wave-uniform loop
    const int l = __builtin_ctzll(mask);
    mask &= mask - 1;
    const float dl = __int_as_float(
        __builtin_amdgcn_readlane(__float_as_int(d2), l));
    if (dl < tmax) {                      // re-check vs tightened threshold
      const int il = g + l;
      const bool keep = bd <= dl;
      const float pd = __shfl_up(bd, 1, 16);    // segmented shift
      const int   pi = __shfl_up(bi, 1, 16);
      const bool fromPrev = ((lane & 15) > 0) && (pd > dl);
      const float nbd = keep ? bd : (fromPrev ? pd : dl);
      const int   nbi = keep ? bi : (fromPrev ? pi : il);
      bd = (seg == S) ? nbd : bd;
      bi = (seg == S) ? nbi : bi;
      tmax = __int_as_float(
          __builtin_amdgcn_readlane(__float_as_int(bd), S * 16 + 15));
    }
  }
}

// ---------------------------------------------------------------------------
// KNN v4 (round-5 proven): 4 queries per wave, segmented top-16 lists.
// ---------------------------------------------------------------------------
__global__ __launch_bounds__(256) void knn_wave_kernel(
    const float4* __restrict__ xyzw, unsigned short* __restrict__ knn_out) {
  const int wid  = threadIdx.x >> 6;
  const int lane = threadIdx.x & 63;
  const int seg  = lane >> 4;
  const int q0 = (blockIdx.x * 4 + wid) * 4;
  const int b = q0 >> 13;
  const float4* cb = xyzw + (size_t)b * NPTS;

  const float4 mA = xyzw[q0 + 0];
  const float4 mB = xyzw[q0 + 1];
  const float4 mC = xyzw[q0 + 2];
  const float4 mD = xyzw[q0 + 3];

  float bd = INFINITY;
  int   bi = 0x7fff;
  float tA = INFINITY, tB = INFINITY, tC = INFINITY, tD = INFINITY;

  for (int g = 0; g < NPTS; g += 64) {
    const float4 t = cb[g + lane];
    const float dA = mA.w + t.w - 2.f * (mA.x * t.x + mA.y * t.y + mA.z * t.z);
    const float dB = mB.w + t.w - 2.f * (mB.x * t.x + mB.y * t.y + mB.z * t.z);
    const float dC = mC.w + t.w - 2.f * (mC.x * t.x + mC.y * t.y + mC.z * t.z);
    const float dD = mD.w + t.w - 2.f * (mD.x * t.x + mD.y * t.y + mD.z * t.z);
    ins16<0>(dA, g, lane, seg, bd, bi, tA);
    ins16<1>(dB, g, lane, seg, bd, bi, tB);
    ins16<2>(dC, g, lane, seg, bd, bi, tC);
    ins16<3>(dD, g, lane, seg, bd, bi, tD);
  }
  knn_out[(size_t)q0 * KNN + lane] = (unsigned short)bi;
}

// ---------------------------------------------------------------------------
// pos_kernel (round-2 proven): pos-MLP hoisted out of attn.
// ---------------------------------------------------------------------------
__global__ __launch_bounds__(256) void pos_kernel(
    const float4* __restrict__ xyzw, const unsigned short* __restrict__ knn_in,
    const float* __restrict__ Wp1, const float* __restrict__ bp1,
    const float* __restrict__ Wp2, const float* __restrict__ bp2,
    bf16* __restrict__ posG) {
  __shared__ float h1S[4][16][64];        // 16 KB
  const int wid = threadIdx.x >> 6, lane = threadIdx.x & 63;
  const int p = blockIdx.x * 4 + wid;
  const int b = p >> 13, n = p & (NPTS - 1);
  const float4* cb = xyzw + (size_t)b * NPTS;
  const float4 me = cb[n];

  float rx = 0.f, ry = 0.f, rz = 0.f;
  if (lane < 16) {
    const int idx = knn_in[(size_t)p * KNN + lane];
    const float4 t = cb[idx];
    rx = t.x - me.x; ry = t.y - me.y; rz = t.z - me.z;
  }
  const float w0 = Wp1[lane], w1 = Wp1[64 + lane], w2 = Wp1[128 + lane];
  const float bb1 = bp1[lane], bb2 = bp2[lane];
#pragma unroll
  for (int k = 0; k < 16; k++) {
    const float r0 = __shfl(rx, k, 64);
    const float r1 = __shfl(ry, k, 64);
    const float r2 = __shfl(rz, k, 64);
    h1S[wid][k][lane] = fmaxf(bb1 + r0 * w0 + r1 * w1 + r2 * w2, 0.f);
  }
  __syncthreads();

  float acc[16];
#pragma unroll
  for (int k = 0; k < 16; k++) acc[k] = bb2;
  for (int jq = 0; jq < 16; jq++) {
    const float w2a = Wp2[(jq * 4 + 0) * 64 + lane];
    const float w2b = Wp2[(jq * 4 + 1) * 64 + lane];
    const float w2c = Wp2[(jq * 4 + 2) * 64 + lane];
    const float w2d = Wp2[(jq * 4 + 3) * 64 + lane];
#pragma unroll
    for (int k = 0; k < 16; k++) {
      const float4 h = *(const float4*)&h1S[wid][k][jq * 4];  // broadcast b128
      acc[k] += h.x * w2a + h.y * w2b + h.z * w2c + h.w * w2d;
    }
  }
#pragma unroll
  for (int k = 0; k < 16; k++)
    posG[((size_t)p * KNN + k) * 64 + lane] = f2b(acc[k]);
}

// ---------------------------------------------------------------------------
// wprep_qkv: transpose Wq/Wk/Wv f32[k][c] -> SPLIT bf16 pairs (hi, lo) in
// MFMA B layout [c][k] (k = 128). hi+lo reproduces f32 to ~2^-16 rel, so the
// split-MFMA proj GEMMs match the old f32-VALU results to f32 noise.
// Outputs live in the AOUT region (after xyzw), overwritten later by attn.
// ---------------------------------------------------------------------------
__global__ __launch_bounds__(256) void wprep_qkv_kernel(
    const float* __restrict__ Wq, const float* __restrict__ Wk,
    const float* __restrict__ Wv,
    bf16* __restrict__ Wqh, bf16* __restrict__ Wql,
    bf16* __restrict__ Wkh, bf16* __restrict__ Wkl,
    bf16* __restrict__ Wvh, bf16* __restrict__ Wvl) {
  const int t = blockIdx.x * 256 + threadIdx.x;   // [0, 12288)
  const int m = t >> 12;
  const int rem = t & 4095;
  const int c = rem >> 4, k8 = (rem & 15) * 8;
  const float* src = (m == 0) ? Wq : (m == 1) ? Wk : Wv;
  bf16* dh = (m == 0) ? Wqh : (m == 1) ? Wkh : Wvh;
  bf16* dl = (m == 0) ? Wql : (m == 1) ? Wkl : Wvl;
#pragma unroll
  for (int j = 0; j < 8; j++) {
    const float x = src[(k8 + j) * 256 + c];
    const bf16 hi = f2b(x);
    dh[c * 128 + k8 + j] = hi;
    dl[c * 128 + k8 + j] = f2b(x - b2f(hi));
  }
}

// ---------------------------------------------------------------------------
// Projections v2 (round 8): MFMA with split-bf16 operands. 16 rows/block,
// 4 waves; wave w owns cols [64w, 64w+64) as 4 16x16 tiles. Each of the 4
// GEMMs (Q, K, V, skip) computed as ah*bh + ah*bl + al*bh (f32-accurate).
// Q and skip share the Wq B-fragments. A-tiles (fh/fl from feat, lh/ll from
// LN1(feat)) in LDS at padded stride 136 bf16 (272 B -> 2-way bank alias,
// free). LN1 f32 in LDS; stats via width-16 shfl (no extra barriers).
// ---------------------------------------------------------------------------
#define PR  16
#define PCP 136
__global__ __launch_bounds__(256) void proj_kernel(
    const float* __restrict__ feat,
    const bf16* __restrict__ Wqh, const bf16* __restrict__ Wql,
    const bf16* __restrict__ Wkh, const bf16* __restrict__ Wkl,
    const bf16* __restrict__ Wvh, const bf16* __restrict__ Wvl,
    const float* __restrict__ bq, const float* __restrict__ bk,
    const float* __restrict__ bv,
    const float* __restrict__ g1, const float* __restrict__ b1,
    bf16* __restrict__ Q, bf16* __restrict__ Kf, bf16* __restrict__ Vf,
    float* __restrict__ skip) {
  __shared__ float fS[PR][DIM];           // 8 KB f32 staging
  __shared__ bf16 fh[PR][PCP], fl[PR][PCP];   // feat hi/lo (4.25 KB each)
  __shared__ bf16 lh[PR][PCP], ll[PR][PCP];   // LN1 hi/lo
  const int tid  = threadIdx.x;
  const size_t r0 = (size_t)blockIdx.x * PR;

  // stage feat: 16 x 128 f32, two float4 per thread
  {
    const float4* src = (const float4*)(feat + r0 * DIM);
    float4* dst = (float4*)&fS[0][0];
#pragma unroll
    for (int i = 0; i < 2; i++) dst[tid + i * 256] = src[tid + i * 256];
  }
  __syncthreads();

  // LN1 per row: 16 threads/row, 8 elems each, width-16 shfl reduce+broadcast
  {
    const int r = tid >> 4, j = tid & 15;
    float v[8];
    float s = 0.f;
#pragma unroll
    for (int i = 0; i < 8; i++) { v[i] = fS[r][j * 8 + i]; s += v[i]; }
#pragma unroll
    for (int o = 8; o; o >>= 1) s += __shfl_down(s, o, 16);
    const float mu = __shfl(s, 0, 16) * (1.f / 128.f);
    float ss = 0.f;
#pragma unroll
    for (int i = 0; i < 8; i++) { const float d = v[i] - mu; ss += d * d; }
#pragma unroll
    for (int o = 8; o; o >>= 1) ss += __shfl_down(ss, o, 16);
    const float rsd = rsqrtf(__shfl(ss, 0, 16) * (1.f / 128.f) + 1e-5f);
#pragma unroll
    for (int i = 0; i < 8; i++) {
      const int c = j * 8 + i;
      const bf16 hv = f2b(v[i]);
      fh[r][c] = hv;
      fl[r][c] = f2b(v[i] - b2f(hv));
      const float lnv = (v[i] - mu) * rsd * g1[c] + b1[c];
      const bf16 lhv = f2b(lnv);
      lh[r][c] = lhv;
      ll[r][c] = f2b(lnv - b2f(lhv));
    }
  }
  __syncthreads();

  // GEMMs: wave w -> cols [64w, 64w+64), K = 128 in 4 steps of 32
  const int w    = tid >> 6;
  const int lane = tid & 63;
  const int g    = lane >> 4, lr = lane & 15;
  const int cw   = w * 64;
  f32x4 qa[4], ka[4], va[4], sa[4];
#pragma unroll
  for (int t = 0; t < 4; t++) {
    qa[t] = (f32x4){0.f, 0.f, 0.f, 0.f};
    ka[t] = qa[t]; va[t] = qa[t]; sa[t] = qa[t];
  }
#pragma unroll
  for (int s = 0; s < 4; s++) {
    const int k0 = s * 32 + g * 8;
    const short8v ah = *(const short8v*)&fh[lr][k0];
    const short8v al = *(const short8v*)&fl[lr][k0];
    const short8v nh = *(const short8v*)&lh[lr][k0];
    const short8v nl = *(const short8v*)&ll[lr][k0];
#pragma unroll
    for (int t = 0; t < 4; t++) {
      const int c = cw + 16 * t + lr;
      const short8v wqh = *(const short8v*)&Wqh[c * 128 + k0];
      const short8v wql = *(const short8v*)&Wql[c * 128 + k0];
      const short8v wkh = *(const short8v*)&Wkh[c * 128 + k0];
      const short8v wkl = *(const short8v*)&Wkl[c * 128 + k0];
      const short8v wvh = *(const short8v*)&Wvh[c * 128 + k0];
      const short8v wvl = *(const short8v*)&Wvl[c * 128 + k0];
      qa[t] = __builtin_amdgcn_mfma_f32_16x16x32_bf16(ah, wqh, qa[t], 0, 0, 0);
      qa[t] = __builtin_amdgcn_mfma_f32_16x16x32_bf16(ah, wql, qa[t], 0, 0, 0);
      qa[t] = __builtin_amdgcn_mfma_f32_16x16x32_bf16(al, wqh, qa[t], 0, 0, 0);
      ka[t] = __builtin_amdgcn_mfma_f32_16x16x32_bf16(ah, wkh, ka[t], 0, 0, 0);
      ka[t] = __builtin_amdgcn_mfma_f32_16x16x32_bf16(ah, wkl, ka[t], 0, 0, 0);
      ka[t] = __builtin_amdgcn_mfma_f32_16x16x32_bf16(al, wkh, ka[t], 0, 0, 0);
      va[t] = __builtin_amdgcn_mfma_f32_16x16x32_bf16(ah, wvh, va[t], 0, 0, 0);
      va[t] = __builtin_amdgcn_mfma_f32_16x16x32_bf16(ah, wvl, va[t], 0, 0, 0);
      va[t] = __builtin_amdgcn_mfma_f32_16x16x32_bf16(al, wvh, va[t], 0, 0, 0);
      sa[t] = __builtin_amdgcn_mfma_f32_16x16x32_bf16(nh, wqh, sa[t], 0, 0, 0);
      sa[t] = __builtin_amdgcn_mfma_f32_16x16x32_bf16(nh, wql, sa[t], 0, 0, 0);
      sa[t] = __builtin_amdgcn_mfma_f32_16x16x32_bf16(nl, wqh, sa[t], 0, 0, 0);
    }
  }

  // stores: C/D mapping col=lane&15, row=4*(lane>>4)+e (m89-verified)
#pragma unroll
  for (int t = 0; t < 4; t++) {
    const int c = cw + 16 * t + lr;
    const float bqv = bq[c], bkv = bk[c], bvv = bv[c];
#pragma unroll
    for (int e = 0; e < 4; e++) {
      const size_t o = (r0 + 4 * g + e) * DOUT + c;
      Q[o]    = f2b(qa[t][e] + bqv);
      Kf[o]   = f2b(ka[t][e] + bkv);
      Vf[o]   = f2b(va[t][e] + bvv);
      skip[o] = sa[t][e] + bqv;
    }
  }
}

// ---------------------------------------------------------------------------
// Attention v3 (round-2 proven).
// ---------------------------------------------------------------------------
__global__ __launch_bounds__(256) void attn_kernel(
    const unsigned short* __restrict__ knn_in,
    bf16* __restrict__ QOA, const bf16* __restrict__ Kf, const bf16* __restrict__ Vf,
    const bf16* __restrict__ posG,
    float* __restrict__ AOUT) {
  __shared__ int nidxS[16];
  const int tid  = threadIdx.x;
  const int w    = tid >> 6;
  const int lane = tid & 63;
  const int p = blockIdx.x;
  const int b = p >> 13, n = p & (NPTS - 1);

  if (tid < 16) nidxS[tid] = knn_in[(size_t)p * KNN + tid];
  const float qreg = b2f(QOA[(size_t)p * DOUT + tid]);
  __syncthreads();

  float kreg[16], vreg[16], posr[16];
  const size_t rowbase = (size_t)b * NPTS;
  const bf16* pg = posG + (size_t)p * KNN * 64 + lane;
#pragma unroll
  for (int k = 0; k < 16; k++) {
    const size_t row = (rowbase + (size_t)nidxS[k]) * DOUT + tid;
    kreg[k] = b2f(Kf[row]);
    vreg[k] = b2f(Vf[row]);
    posr[k] = b2f(pg[k * 64]);
  }

  float lg[16];
#pragma unroll
  for (int k = 0; k < 16; k++) lg[k] = qreg * (kreg[k] + posr[k]);
#pragma unroll
  for (int o = 32; o; o >>= 1) {
#pragma unroll
    for (int k = 0; k < 16; k++) lg[k] += __shfl_xor(lg[k], o, 64);
  }
  float m = -INFINITY;
#pragma unroll
  for (int k = 0; k < 16; k++) { lg[k] *= 0.125f; m = fmaxf(m, lg[k]); }
  float sum = 0.f;
#pragma unroll
  for (int k = 0; k < 16; k++) { lg[k] = expf(lg[k] - m); sum += lg[k]; }
  const float inv = 1.f / sum;
#pragma unroll
  for (int k = 0; k < 16; k++) lg[k] *= inv;
  float av = 0.f;
#pragma unroll
  for (int k = 0; k < 16; k++) if (lane == k) av = lg[k];
  if (lane < 16)
    AOUT[(((size_t)b * 4 + w) * NPTS + n) * KNN + lane] = av;
  float o = 0.f;
#pragma unroll
  for (int k = 0; k < 16; k++) o += lg[k] * (vreg[k] + posr[k]);
  QOA[(size_t)p * DOUT + tid] = f2b(o);
}

// ---------------------------------------------------------------------------
// wprep: one-time transpose+convert Wf1/Wf2 f32[k][c] -> bf16 Wt[c][k]
// (single bf16 -- proven absmax-neutral in round 7). Runs after attn; Wt
// lives in the dead Kf region.
// ---------------------------------------------------------------------------
__global__ __launch_bounds__(256) void wprep_kernel(
    const float* __restrict__ Wf1, const float* __restrict__ Wf2,
    bf16* __restrict__ Wt1, bf16* __restrict__ Wt2) {
  const int t = blockIdx.x * 256 + threadIdx.x;          // [0, 16384)
  const float* src = (t & 8192) ? Wf2 : Wf1;
  bf16*        dst = (t & 8192) ? Wt2 : Wt1;
  const int rem = t & 8191;
  const int c = rem >> 5, k8 = (rem & 31) * 8;
#pragma unroll
  for (int j = 0; j < 8; j++)
    dst[c * 256 + k8 + j] = f2b(src[(k8 + j) * 256 + c]);
}

// ---------------------------------------------------------------------------
// FFN v4 (round-7 proven): MFMA, 16 rows/block, aliased LDS, LN2 + residual.
// ---------------------------------------------------------------------------
#define FRB 16
#define FCP 264
__global__ __launch_bounds__(256) void ffn_kernel(
    const bf16* __restrict__ OA,
    const bf16* __restrict__ Wt1, const float* __restrict__ bf1,
    const bf16* __restrict__ Wt2, const float* __restrict__ bf2,
    const float* __restrict__ g2, const float* __restrict__ b2p,
    float* __restrict__ out) {
  __shared__ float zs[FRB][FCP];          // 16896 B; aliased as xs|ys (bf16)
  __shared__ float mu16[FRB], rs16[FRB];
  bf16* base = (bf16*)&zs[0][0];
  const int ysoff = FRB * FCP;
  const int tid  = threadIdx.x;
  const int w    = tid >> 6;
  const int lane = tid & 63;
  const int g    = lane >> 4, lr = lane & 15;
  const int cw   = w * 64;
  const size_t r0 = (size_t)blockIdx.x * FRB;

  {
    const short8v* src = (const short8v*)(OA + r0 * DOUT);
#pragma unroll
    for (int i = 0; i < 2; i++) {
      const int ch = tid + i * 256;
      const int row = ch >> 5, c8 = (ch & 31) * 8;
      *(short8v*)&base[row * FCP + c8] = src[ch];
    }
  }
  __syncthreads();

  f32x4 a0 = {0.f, 0.f, 0.f, 0.f}, a1 = a0, a2 = a0, a3 = a0;

#define GEMM8(OFF, WT)                                                         \
  _Pragma("unroll")                                                            \
  for (int s = 0; s < 8; s++) {                                                \
    const int k0 = s * 32 + g * 8;                                             \
    const short8v av = *(const short8v*)&base[(OFF) + lr * FCP + k0];          \
    a0 = __builtin_amdgcn_mfma_f32_16x16x32_bf16(                              \
        av, *(const short8v*)&(WT)[(cw +  0 + lr) * 256 + k0], a0, 0, 0, 0);   \
    a1 = __builtin_amdgcn_mfma_f32_16x16x32_bf16(                              \
        av, *(const short8v*)&(WT)[(cw + 16 + lr) * 256 + k0], a1, 0, 0, 0);   \
    a2 = __builtin_amdgcn_mfma_f32_16x16x32_bf16(                              \
        av, *(const short8v*)&(WT)[(cw + 32 + lr) * 256 + k0], a2, 0, 0, 0);   \
    a3 = __builtin_amdgcn_mfma_f32_16x16x32_bf16(                              \
        av, *(const short8v*)&(WT)[(cw + 48 + lr) * 256 + k0], a3, 0, 0, 0);   \
  }

  GEMM8(0, Wt1)

#define STORE_Y(ACC, T)                                                        \
  {                                                                            \
    const int c = cw + 16 * (T) + lr;                                          \
    const float bb = bf1[c];                                                   \
    _Pragma("unroll")                                                          \
    for (int e = 0; e < 4; e++)                                                \
      base[ysoff + (4 * g + e) * FCP + c] = f2b(fmaxf(ACC[e] + bb, 0.f));      \
  }
  STORE_Y(a0, 0) STORE_Y(a1, 1) STORE_Y(a2, 2) STORE_Y(a3, 3)
  __syncthreads();

  a0 = (f32x4){0.f, 0.f, 0.f, 0.f}; a1 = a0; a2 = a0; a3 = a0;
  GEMM8(ysoff, Wt2)
  __syncthreads();

#define STORE_Z(ACC, T)                                                        \
  {                                                                            \
    const int c = cw + 16 * (T) + lr;                                          \
    const float bb = bf2[c];                                                   \
    _Pragma("unroll")                                                          \
    for (int e = 0; e < 4; e++) zs[4 * g + e][c] = ACC[e] + bb;                \
  }
  STORE_Z(a0, 0) STORE_Z(a1, 1) STORE_Z(a2, 2) STORE_Z(a3, 3)
  __syncthreads();

  const int r = tid >> 4, j = tid & 15;
  float s = 0.f;
#pragma unroll
  for (int k2 = 0; k2 < 16; k2++) s += zs[r][j + 16 * k2];
#pragma unroll
  for (int o = 8; o; o >>= 1) s += __shfl_down(s, o, 16);
  if (!j) mu16[r] = s * (1.f / 256.f);
  __syncthreads();
  const float mu = mu16[r];
  float ss = 0.f;
#pragma unroll
  for (int k2 = 0; k2 < 16; k2++) { const float dd = zs[r][j + 16 * k2] - mu; ss += dd * dd; }
#pragma unroll
  for (int o = 8; o; o >>= 1) ss += __shfl_down(ss, o, 16);
  if (!j) rs16[r] = rsqrtf(ss * (1.f / 256.f) + 1e-5f);
  __syncthreads();

  const float gv = g2[tid], bbv = b2p[tid];
#pragma unroll
  for (int rr = 0; rr < FRB; rr++) {
    const size_t o = (r0 + rr) * DOUT + tid;
    const float sk = out[o];
    out[o] = (zs[rr][tid] - mu16[rr]) * rs16[rr] * gv + bbv + sk;
  }
}

extern "C" void kernel_launch(void* const* d_in, const int* in_sizes, int n_in,
                              void* d_out, int out_size, void* d_ws, size_t ws_size,
                              hipStream_t stream) {
  const float* xyz  = (const float*)d_in[0];
  const float* feat = (const float*)d_in[1];
  const float* Wq   = (const float*)d_in[2];
  const float* bq   = (const float*)d_in[3];
  const float* Wk   = (const float*)d_in[4];
  const float* bk   = (const float*)d_in[5];
  const float* Wv   = (const float*)d_in[6];
  const float* bv   = (const float*)d_in[7];
  const float* Wp1  = (const float*)d_in[8];
  const float* bp1  = (const float*)d_in[9];
  const float* Wp2  = (const float*)d_in[10];
  const float* bp2  = (const float*)d_in[11];
  const float* Wf1  = (const float*)d_in[12];
  const float* bf1  = (const float*)d_in[13];
  const float* Wf2  = (const float*)d_in[14];
  const float* bf2  = (const float*)d_in[15];
  const float* g1   = (const float*)d_in[16];
  const float* b1   = (const float*)d_in[17];
  const float* g2   = (const float*)d_in[18];
  const float* b2   = (const float*)d_in[19];

  float* out  = (float*)d_out;
  float* aout = out + (size_t)TOTPTS * DOUT;  // attn-weights output region

  // workspace layout (113 MB peak):
  //   [0, 1 MB)     knn indices u16
  //   [1, 17 MB)    QOA bf16 (proj -> attn-out, ffn input)
  //   [17, 33 MB)   Kf bf16; dead after attn -> reused for Wt1/Wt2 (wprep)
  //   [33, 49 MB)   Vf bf16
  //   [49, 113 MB)  posG bf16
  // AOUT region of d_out doubles as scratch before attn overwrites it:
  //   [0, 512 KB)        xyzw float4 (knn + pos)
  //   [512 KB, 896 KB)   Wq/Wk/Wv split-bf16 transposes (proj B-operands)
  unsigned short* knn  = (unsigned short*)d_ws;
  float4*         xyzw = (float4*)aout;
  bf16* QOA  = (bf16*)((char*)d_ws + (size_t)(1 << 20));
  bf16* Kf   = QOA + (size_t)TOTPTS * DOUT;
  bf16* Vf   = Kf  + (size_t)TOTPTS * DOUT;
  bf16* posG = (bf16*)((char*)d_ws + (size_t)(49 << 20));
  bf16* Wt1  = Kf;                        // ffn weights, alive only after attn
  bf16* Wt2  = Kf + 65536;
  bf16* Wqh  = (bf16*)((char*)aout + (512 << 10));
  bf16* Wql  = Wqh + 32768;
  bf16* Wkh  = Wql + 32768;
  bf16* Wkl  = Wkh + 32768;
  bf16* Wvh  = Wkl + 32768;
  bf16* Wvl  = Wvh + 32768;

  pack_kernel<<<TOTPTS / 256, 256, 0, stream>>>(xyz, xyzw);
  wprep_qkv_kernel<<<48, 256, 0, stream>>>(Wq, Wk, Wv, Wqh, Wql, Wkh, Wkl, Wvh, Wvl);
  knn_wave_kernel<<<TOTPTS / 16, 256, 0, stream>>>(xyzw, knn);
  pos_kernel<<<TOTPTS / 4, 256, 0, stream>>>(xyzw, knn, Wp1, bp1, Wp2, bp2, posG);
  proj_kernel<<<TOTPTS / PR, 256, 0, stream>>>(feat, Wqh, Wql, Wkh, Wkl, Wvh, Wvl,
                                               bq, bk, bv, g1, b1,
                                               QOA, Kf, Vf, /*skip->*/out);
  attn_kernel<<<TOTPTS, 256, 0, stream>>>(knn, QOA, Kf, Vf, posG, aout);
  wprep_kernel<<<64, 256, 0, stream>>>(Wf1, Wf2, Wt1, Wt2);
  ffn_kernel<<<TOTPTS / FRB, 256, 0, stream>>>(QOA, Wt1, bf1, Wt2, bf2, g2, b2, out);
}